// Round 1
// 190.552 us; speedup vs baseline: 1.0476x; 1.0476x over previous
//
#include <hip/hip_runtime.h>

#define NPTS 8192
#define NB 4
#define NCH 128
#define DQK 48
#define TK 64
#define SPLIT 4
#define KEYS_PER (NPTS / SPLIT)   // 2048
#define ROUNDS (KEYS_PER / TK)    // 32
#define SH2 28.853901f            // 20 * log2(e)
#define LOG2E 1.4426950408889634f

typedef unsigned short ushort_t;
typedef unsigned int uint_t;
typedef __attribute__((ext_vector_type(8))) short bf16x8;
typedef __attribute__((ext_vector_type(4))) float f32x4;
typedef __attribute__((ext_vector_type(16))) float f32x16;

static __device__ __forceinline__ ushort_t f2bf(float x) {
  union { float f; uint_t u; } v; v.f = x;
  uint_t r = v.u + 0x7fffu + ((v.u >> 16) & 1u);
  return (ushort_t)(r >> 16);
}
static __device__ __forceinline__ float bf2f(ushort_t u) {
  union { uint_t i; float f; } v; v.i = ((uint_t)u) << 16; return v.f;
}
// sigma16: swap middle two 4-blocks of each 16-group (involution).
// Makes S^T C-layout regs directly usable as the PV A-fragment.
static __device__ __forceinline__ int sig16(int n) {
  int g2 = (n >> 2) & 3;
  return (g2 == 1 || g2 == 2) ? (n ^ 0xC) : n;
}

typedef __attribute__((address_space(1))) void void_g;
typedef __attribute__((address_space(3))) void void_l;
static __device__ __forceinline__ void gload_lds16(const ushort_t* g, ushort_t* l) {
  __builtin_amdgcn_global_load_lds((void_g*)(ushort_t*)g, (void_l*)l, 16, 0, 0);
}

// ---------------------------------------------------------------------------
// Weight prep: W -> A-fragment-ordered bf16 Wb[z][ks][lane][8] (log2e folded
// into z=0), plus fused scaled bias bias_pre[192]. 6 blocks, one z each.
// ---------------------------------------------------------------------------
__global__ __launch_bounds__(512, 1)
void wprep_kernel(const float* __restrict__ Wq, const float* __restrict__ bq,
                  const float* __restrict__ Wk, const float* __restrict__ bk,
                  const float* __restrict__ Wv, const float* __restrict__ bv,
                  ushort_t* __restrict__ Wb, float* __restrict__ bias_pre) {
  const int z = blockIdx.x;
  const int ks = threadIdx.x >> 6;
  const int lane = threadIdx.x & 63;
  const int l31 = lane & 31, h = lane >> 5;
  const float* W = (z == 0) ? Wq : (z == 1) ? Wk : (Wv + (size_t)(z - 2) * 32 * 128);
  const float sc = (z == 0) ? LOG2E : 1.0f;
  const float* wr = W + l31 * 128 + ks * 16 + h * 8;
  union { ushort_t u[8]; bf16x8 v; } p;
#pragma unroll
  for (int j = 0; j < 8; ++j) p.u[j] = f2bf(wr[j] * sc);
  *(bf16x8*)(Wb + ((size_t)(z * 8 + ks) * 64 + lane) * 8) = p.v;
  if (z == 0 && threadIdx.x < 192) {
    int i = threadIdx.x;
    bias_pre[i] = (i < 32) ? bq[i] * LOG2E : (i < 64) ? bk[i - 32] : bv[i - 64];
  }
}

// ---------------------------------------------------------------------------
// MFMA projections, fused over all 6 bands: x B-frags loaded+converted ONCE
// per wave (32 n-cols), reused for 48 MFMAs. A-frags from pre-packed Wb
// (coalesced 16B loads). C layout: col = lane&31, row = (r&3)+8*(r>>2)+4h.
// z=0: Qb rows (+xhat, log2e-scaled), z=1: Kb rows (+xhat), z=2..5: Vt with
// sigma16-permuted key index.
// NEW: softmax shift folded into slot 35: Q[35] = -SH2, K[35] = 1.0 (uniform
// per-row additive constant -> cancels exactly in O/L normalization). Lets
// attn do exp2(S) with no per-element subtract.
// ---------------------------------------------------------------------------
__global__ __launch_bounds__(256, 4)
void projm2_kernel(const float* __restrict__ x, const float* __restrict__ xyz,
                   const ushort_t* __restrict__ Wb,
                   const float* __restrict__ bias_pre,
                   ushort_t* __restrict__ Qb, ushort_t* __restrict__ Kb,
                   ushort_t* __restrict__ Vt) {
  const int tid = threadIdx.x;
  const int lane = tid & 63, wv = tid >> 6;
  const int l31 = lane & 31, h = lane >> 5;
  const int b = blockIdx.y;
  const int n = blockIdx.x * 128 + wv * 32 + l31;

  // B-frags from x (coalesced per c-row), converted once, reused 6x
  bf16x8 bfr[8];
  const float* xb = x + (size_t)b * NCH * NPTS + n;
#pragma unroll
  for (int ks = 0; ks < 8; ++ks) {
    const float* xc = xb + (size_t)(ks * 16 + h * 8) * NPTS;
    union { ushort_t u[8]; bf16x8 v; } p;
#pragma unroll
    for (int j = 0; j < 8; ++j) p.u[j] = f2bf(xc[(size_t)j * NPTS]);
    bfr[ks] = p.v;
  }

  // xhat (bands 0,1)
  float xa = xyz[((size_t)b * NPTS + n) * 3 + 0];
  float xc2 = xyz[((size_t)b * NPTS + n) * 3 + 1];
  float xd = xyz[((size_t)b * NPTS + n) * 3 + 2];
  float rinv = 1.0f / (sqrtf(xa * xa + xc2 * xc2 + xd * xd) + 1e-8f);

#pragma unroll 1
  for (int z = 0; z < 6; ++z) {
    f32x16 S;
#pragma unroll
    for (int r = 0; r < 16; ++r)
      S[r] = bias_pre[z * 32 + (r & 3) + 8 * (r >> 2) + 4 * h];
#pragma unroll
    for (int ks = 0; ks < 8; ++ks) {
      bf16x8 af = *(const bf16x8*)(Wb + ((size_t)(z * 8 + ks) * 64 + lane) * 8);
      S = __builtin_amdgcn_mfma_f32_32x32x16_bf16(af, bfr[ks], S, 0, 0, 0);
    }
    if (z <= 1) {
      float sc = (z == 0) ? LOG2E : 1.0f;
      ushort_t* dst = (z == 0 ? Qb : Kb) + ((size_t)b * NPTS + n) * DQK;
#pragma unroll
      for (int r = 0; r < 16; ++r)
        dst[(r & 3) + 8 * (r >> 2) + 4 * h] = f2bf(S[r]);
      float rn = 0.31622776601683794f * sc * rinv;
      union { ushort_t u[16]; bf16x8 v[2]; } t;
#pragma unroll
      for (int j = 0; j < 16; ++j) t.u[j] = 0;
      t.u[0] = f2bf(xa * rn); t.u[1] = f2bf(xc2 * rn); t.u[2] = f2bf(xd * rn);
      t.u[3] = (z == 0) ? f2bf(-SH2) : f2bf(1.0f);  // folded softmax shift
      *(bf16x8*)(dst + 32) = t.v[0];
      *(bf16x8*)(dst + 40) = t.v[1];
    } else {
      const int np = (n & ~15) | sig16(n & 15);  // key-permuted V storage
      const int c0 = (z - 2) * 32;
#pragma unroll
      for (int r = 0; r < 16; ++r)
        Vt[((size_t)b * NCH + c0 + (r & 3) + 8 * (r >> 2) + 4 * h) * NPTS + np] =
            f2bf(S[r]);
    }
  }
}

// ---------------------------------------------------------------------------
// MFMA flash attention, 32x32x16, 32 q/wave, 8 waves = 256 q/block.
// R8 RESTRUCTURE: previous 64q/wave version needed 256 regs/wave -> 2
// waves/SIMD, 1 block/CU -> lockstep waves -> MFMA(37.9us) + VALU(45.6us) +
// LDS(28us) pipes ran SERIALIZED (sum == measured 108.6us). Halving per-wave
// state (O[4] = 64 acc regs) targets 128 regs/wave -> 4 waves/SIMD from 2
// independent blocks/CU (LDS 2x45KB=90KB) -> cross-pipe overlap.
// Softmax shift pre-folded into slot 35 (no per-element subtract).
// V is sigma16-permuted so S^T C-regs pack directly into the PV A-frag.
// ---------------------------------------------------------------------------
__global__ __launch_bounds__(512, 4)
void attn32_kernel(const ushort_t* __restrict__ Qb, const ushort_t* __restrict__ Kb,
                   const ushort_t* __restrict__ Vt,
                   ushort_t* __restrict__ PACC, float* __restrict__ PL) {
  // frag f: K = kb*3+c (6), V = 6 + fch*4 + kk (16); each 64 lanes x 16B
  __shared__ __align__(16) ushort_t L[2][22][512];
  const int tid = threadIdx.x;
  const int lane = tid & 63, w = tid >> 6;
  const int l31 = lane & 31, h = lane >> 5;

  const int lin = blockIdx.x;
  const int bs = lin & 15;          // XCD x sees bs in {x, x+8}: 2 (b,seg) combos
  const int b = bs & 3, sseg = bs >> 2;
  const int qblk = lin >> 4;        // 0..31 (256-q blocks)
  const int q0w = qblk * 256 + w * 32;
  const int m00 = sseg * KEYS_PER;

  // persistent Q^T B-frags: q = q0w + l31, d = c*16 + h*8 + j
  bf16x8 qf[3];
#pragma unroll
  for (int c = 0; c < 3; ++c)
    qf[c] = *(const bf16x8*)(Qb + ((size_t)b * NPTS + q0w + l31) * DQK +
                             c * 16 + h * 8);

  // staging: wave w handles frags {w, w+8, (w+16 if w<6)} (22 total)
  const ushort_t* gp[3];
  int fid[3], adv[3];
  const int nf = (w < 6) ? 3 : 2;
#pragma unroll
  for (int i = 0; i < 3; ++i) {
    int fi = w + 8 * i;
    fid[i] = fi;
    if (fi < 6) {
      int kb = fi / 3, c = fi - kb * 3;
      gp[i] = Kb + ((size_t)b * NPTS + m00 + kb * 32 + l31) * DQK + c * 16 + h * 8;
      adv[i] = TK * DQK;
    } else if (fi < 22) {
      int vi = fi - 6, fch = vi >> 2, kk = vi & 3;
      gp[i] = Vt + ((size_t)b * NCH + fch * 32 + l31) * NPTS + m00 + kk * 16 + h * 8;
      adv[i] = TK;
    }
  }

  f32x16 O[4];
#pragma unroll
  for (int f = 0; f < 4; ++f) O[f] = (f32x16)(0.f);
  float ls0 = 0.f, ls1 = 0.f;

  // prologue: stage round 0 into buffer 0
#pragma unroll
  for (int i = 0; i < 3; ++i)
    if (i < nf) gload_lds16(gp[i], &L[0][fid[i]][0]);

#pragma unroll 1
  for (int t = 0; t < ROUNDS; ++t) {
    __syncthreads();  // auto vmcnt(0): buf[t&1] DMA (issued a full round ago) drained
    const int cur = t & 1;
    if (t + 1 < ROUNDS) {
#pragma unroll
      for (int i = 0; i < 3; ++i)
        if (i < nf) {
          gp[i] += adv[i];
          gload_lds16(gp[i], &L[cur ^ 1][fid[i]][0]);  // overlaps compute below
        }
    }

#pragma unroll
    for (int kb = 0; kb < 2; ++kb) {
      bf16x8 kf0 = *(const bf16x8*)(&L[cur][kb * 3 + 0][0] + lane * 8);
      bf16x8 kf1 = *(const bf16x8*)(&L[cur][kb * 3 + 1][0] + lane * 8);
      bf16x8 kf2 = *(const bf16x8*)(&L[cur][kb * 3 + 2][0] + lane * 8);

      __builtin_amdgcn_s_setprio(1);
      f32x16 S = __builtin_amdgcn_mfma_f32_32x32x16_bf16(kf0, qf[0],
                                                         (f32x16)(0.f), 0, 0, 0);
      S = __builtin_amdgcn_mfma_f32_32x32x16_bf16(kf1, qf[1], S, 0, 0, 0);
      S = __builtin_amdgcn_mfma_f32_32x32x16_bf16(kf2, qf[2], S, 0, 0, 0);
      __builtin_amdgcn_s_setprio(0);

      // shift already folded into S via slot 35: p = exp2(S) directly
      uint_t pk[8];
#pragma unroll
      for (int i = 0; i < 8; ++i) {
        float p0 = __builtin_amdgcn_exp2f(S[2 * i]);
        float p1 = __builtin_amdgcn_exp2f(S[2 * i + 1]);
        ls0 += p0;
        ls1 += p1;
        pk[i] = __builtin_amdgcn_perm(__float_as_uint(p1), __float_as_uint(p0),
                                      0x07060302u);
      }

      // sigma16-permuted V => C-regs pack directly into PV A-frags
#pragma unroll
      for (int kkl = 0; kkl < 2; ++kkl) {
        union { uint_t u[4]; bf16x8 v; } au;
        au.u[0] = pk[4 * kkl + 0];
        au.u[1] = pk[4 * kkl + 1];
        au.u[2] = pk[4 * kkl + 2];
        au.u[3] = pk[4 * kkl + 3];
        bf16x8 A = au.v;
        __builtin_amdgcn_s_setprio(1);
#pragma unroll
        for (int f = 0; f < 4; ++f) {
          bf16x8 vf = *(const bf16x8*)(&L[cur][6 + f * 4 + kb * 2 + kkl][0] + lane * 8);
          O[f] = __builtin_amdgcn_mfma_f32_32x32x16_bf16(A, vf, O[f], 0, 0, 0);
        }
        __builtin_amdgcn_s_setprio(0);
      }
    }
  }

  // epilogue: same PACC layout as 64q version (W16 = (qblk&1)*8 + w)
  float lsum = ls0 + ls1;
  lsum += __shfl_xor(lsum, 32);
  const size_t pbase = (size_t)(bs * 16 + (qblk >> 1)) * 16 + (qblk & 1) * 8 + w;
#pragma unroll
  for (int f = 0; f < 4; ++f) {
    union { ushort_t u[16]; bf16x8 v[2]; } pu;
#pragma unroll
    for (int r = 0; r < 16; ++r) pu.u[r] = f2bf(O[f][r]);
    size_t idx = (pbase * 4 + f) * 1024 + (size_t)lane * 16;
    *(bf16x8*)(PACC + idx) = pu.v[0];
    *(bf16x8*)(PACC + idx + 8) = pu.v[1];
  }
  if (lane < 32) PL[(size_t)bs * NPTS + q0w + lane] = lsum;
}

// ---------------------------------------------------------------------------
// Merge 4 key-split partials + gamma + x, COALESCED output via LDS bounce.
// grid (qblk2 32, b 4, f 4); each block: 256 q x 32 ch.
// Phase 1: coalesced PACC reads, sum over s, x Linv, stage fp32 in LDS.
// Phase 2: wave w -> 8 ch rows; lane -> q=lane*4: contiguous 1KB load/stores.
// ---------------------------------------------------------------------------
#define MPITCH 268
__global__ __launch_bounds__(256, 4)
void merge4c_kernel(const ushort_t* __restrict__ PACC, const float* __restrict__ PL,
                    const float* __restrict__ x, const float* __restrict__ gamma,
                    float* __restrict__ out) {
  __shared__ float Linv[256];
  __shared__ float ldso[32 * MPITCH];
  const int tid = threadIdx.x;
  const int qblk2 = blockIdx.x, b = blockIdx.y, f = blockIdx.z;
  const int q0 = qblk2 * 256;

  float Ls = 0.f;
#pragma unroll
  for (int s = 0; s < 4; ++s)
    Ls += PL[(size_t)(s * 4 + b) * NPTS + q0 + tid];
  Linv[tid] = gamma[0] / Ls;
  __syncthreads();

  const int ww = tid >> 6, lane = tid & 63, l31 = lane & 31, h = lane >> 5;

#pragma unroll
  for (int g = 0; g < 2; ++g) {
    float acc[16];
#pragma unroll
    for (int r = 0; r < 16; ++r) acc[r] = 0.f;
#pragma unroll
    for (int s = 0; s < 4; ++s) {
      size_t idx = (((((size_t)(s * 4 + b) * 16 + (qblk2 >> 1)) * 8 +
                      (qblk2 & 1) * 4 + ww) * 2 + g) * 4 + f) * 1024 +
                   (size_t)lane * 16;
      bf16x8 a0 = *(const bf16x8*)(PACC + idx);
      bf16x8 a1 = *(const bf16x8*)(PACC + idx + 8);
#pragma unroll
      for (int r = 0; r < 8; ++r) {
        acc[r] += bf2f((ushort_t)a0[r]);
        acc[8 + r] += bf2f((ushort_t)a1[r]);
      }
    }
    const int qb = ww * 64 + g * 32 + 4 * h;
#pragma unroll
    for (int rr = 0; rr < 4; ++rr) {
      int q = qb + 8 * rr;
      f32x4 v;
#pragma unroll
      for (int i = 0; i < 4; ++i) v[i] = acc[rr * 4 + i] * Linv[q + i];
      *(f32x4*)&ldso[l31 * MPITCH + q] = v;  // ch_local = l31
    }
  }
  __syncthreads();

  // phase 2: coalesced: wave ww -> ch rows ww*8..+7, lane -> q = lane*4
  const float* xb = x + ((size_t)b * NCH + f * 32) * NPTS + q0;
  float* ob = out + ((size_t)b * NCH + f * 32) * NPTS + q0;
#pragma unroll
  for (int rr = 0; rr < 8; ++rr) {
    int ch = ww * 8 + rr;
    f32x4 v = *(const f32x4*)&ldso[ch * MPITCH + lane * 4];
    f32x4 xv = *(const f32x4*)(xb + (size_t)ch * NPTS + lane * 4);
    v += xv;
    *(f32x4*)(ob + (size_t)ch * NPTS + lane * 4) = v;
  }
}

// ---------------------------------------------------------------------------
extern "C" void kernel_launch(void* const* d_in, const int* in_sizes, int n_in,
                              void* d_out, int out_size, void* d_ws,
                              size_t ws_size, hipStream_t stream) {
  const float* x     = (const float*)d_in[0];
  const float* xyz   = (const float*)d_in[1];
  const float* Wq    = (const float*)d_in[2];
  const float* bq    = (const float*)d_in[3];
  const float* Wk    = (const float*)d_in[4];
  const float* bk    = (const float*)d_in[5];
  const float* Wv    = (const float*)d_in[6];
  const float* bv    = (const float*)d_in[7];
  const float* gamma = (const float*)d_in[8];
  float* out = (float*)d_out;

  const size_t BN = (size_t)NB * NPTS;
  ushort_t* Qb = (ushort_t*)d_ws;
  ushort_t* Kb = Qb + BN * DQK;
  ushort_t* Vt = Kb + BN * DQK;
  ushort_t* PACC = Vt + BN * NCH;   // 16 bs * 16 qblk * 8 w * 2 g * 4 f * 1024
  float* PL = (float*)(PACC + (size_t)16 * 16 * 8 * 2 * 4 * 1024);
  ushort_t* Wb = (ushort_t*)(PL + 16 * BN / 2);  // 6*8*64*8 = 24576 ushort
  float* bias_pre = (float*)(Wb + 6 * 8 * 64 * 8);

  wprep_kernel<<<6, 512, 0, stream>>>(Wq, bq, Wk, bk, Wv, bv, Wb, bias_pre);
  projm2_kernel<<<dim3(NPTS / 128, NB), 256, 0, stream>>>(
      x, xyz, Wb, bias_pre, Qb, Kb, Vt);
  attn32_kernel<<<512, 512, 0, stream>>>(Qb, Kb, Vt, PACC, PL);
  merge4c_kernel<<<dim3(32, NB, 4), 256, 0, stream>>>(PACC, PL, x, gamma, out);
  (void)in_sizes; (void)n_in; (void)out_size; (void)ws_size;
}